// Round 8
// baseline (15804.485 us; speedup 1.0000x reference)
//
#include <hip/hip_runtime.h>
#include <hip/hip_bf16.h>

#define BB 16
#define NPTS 1024
#define KNB 20
#define HC 512

// x stored row-major (b, n, c): x[b,n,c] at X[(b*1024+n)*3 + c]  (per reference setup_inputs)
__device__ __forceinline__ float XV(const float* __restrict__ X, int b, int n, int c)
{
    return X[((size_t)b * NPTS + n) * 3 + c];
}

// ---------------- sentinel (diagnostic) ----------------
__global__ void sentinel_kernel(float* __restrict__ out, float val)
{
    const int i = blockIdx.x * 256 + threadIdx.x;
    if (i < BB * 40) out[i] = val;
}

// ---------------- squared norms ----------------
__global__ void xx_kernel(const float* __restrict__ H, const float* __restrict__ X,
                          float* __restrict__ xx, int cin, int off_in, int use_x)
{
    const int p = blockIdx.x * blockDim.x + threadIdx.x;
    if (p >= BB * NPTS) return;
    float s = 0.f;
    if (use_x) {
        const int b = p >> 10, n = p & 1023;
        for (int c = 0; c < 3; ++c) { const float v = XV(X, b, n, c); s += v * v; }
    } else {
        const float* r = H + (size_t)p * HC + off_in;
        for (int c = 0; c < cin; ++c) s += r[c] * r[c];
    }
    xx[p] = s;
}

// ---------------- knn top-20, wave-parallel (equivalent to literal top_k) ----------------
__global__ __launch_bounds__(256) void knn_kernel(
    const float* __restrict__ H, const float* __restrict__ X, const float* __restrict__ xx,
    int* __restrict__ idxo, int cin, int off_in, int use_x)
{
    __shared__ float qv[128];
    __shared__ float dist[NPTS];
    __shared__ unsigned long long wred[4];
    __shared__ int winner;

    const int blk = blockIdx.x;
    const int b = blk >> 10, q = blk & 1023;
    const int tid = threadIdx.x;
    const int base = b * NPTS;

    if (use_x) {
        if (tid < 3) qv[tid] = XV(X, b, q, tid);
    } else {
        for (int c = tid; c < cin; c += 256) qv[c] = H[(size_t)(base + q) * HC + off_in + c];
    }
    __syncthreads();
    const float xxq = xx[base + q];

    for (int j = 0; j < 4; ++j) {
        const int m = tid + 256 * j;
        float acc = 0.f;
        if (use_x) {
            acc = qv[0] * XV(X, b, m, 0) + qv[1] * XV(X, b, m, 1) + qv[2] * XV(X, b, m, 2);
        } else {
            const float* r = H + (size_t)(base + m) * HC + off_in;
            for (int c = 0; c < cin; ++c) acc += qv[c] * r[c];
        }
        dist[m] = (2.f * acc - xxq) - xx[base + m];
    }
    __syncthreads();

    const int lane = tid & 63, wv = tid >> 6;
    for (int it = 0; it < KNB; ++it) {
        unsigned long long best = 0ull;
        for (int j = 0; j < 4; ++j) {
            const int m = tid + 256 * j;
            unsigned u = __float_as_uint(dist[m]);
            u = (u & 0x80000000u) ? ~u : (u | 0x80000000u);   // sortable float
            const unsigned long long key = ((unsigned long long)u << 32) | (unsigned)(1023 - m);
            if (key > best) best = key;
        }
        for (int off = 32; off > 0; off >>= 1) {
            const unsigned long long o = __shfl_down(best, off, 64);
            if (o > best) best = o;
        }
        if (lane == 0) wred[wv] = best;
        __syncthreads();
        if (tid == 0) {
            unsigned long long bb = wred[0];
            for (int i2 = 1; i2 < 4; ++i2) if (wred[i2] > bb) bb = wred[i2];
            const int widx = 1023 - (int)(bb & 0xFFFFFFFFull);
            winner = widx;
            idxo[(size_t)(base + q) * KNB + it] = widx;
        }
        __syncthreads();
        if (tid == (winner & 255)) dist[winner] = -INFINITY;
        __syncthreads();
    }
}

// ---------------- edge conv, literal ----------------
template<int CIN, int COUT, bool USEX>
__global__ __launch_bounds__(COUT) void conv_kernel(
    const float* __restrict__ H, const float* __restrict__ X, const int* __restrict__ idx,
    const float* __restrict__ W, const float* __restrict__ Bs, const float* __restrict__ G,
    const float* __restrict__ Be, const float* __restrict__ Bm, const float* __restrict__ Bv,
    float* __restrict__ Hout, int off_in, int off_out)
{
    __shared__ float ctr[CIN];
    __shared__ float nb[KNB][CIN];
    __shared__ int sidx[KNB];
    const int blk = blockIdx.x;
    const int b = blk >> 10, q = blk & 1023;
    const int tid = threadIdx.x;
    const int base = b * NPTS;

    if (tid < KNB) sidx[tid] = idx[(size_t)(base + q) * KNB + tid];
    for (int c = tid; c < CIN; c += COUT)
        ctr[c] = USEX ? XV(X, b, q, c)
                      : H[(size_t)(base + q) * HC + off_in + c];
    __syncthreads();
    for (int t = tid; t < KNB * CIN; t += COUT) {
        const int k = t / CIN, c = t - k * CIN;
        const int src = sidx[k];
        nb[k][c] = USEX ? XV(X, b, src, c)
                        : H[(size_t)(base + src) * HC + off_in + c];
    }
    __syncthreads();

    const int o = tid;
    const float* wr = W + (size_t)o * 2 * CIN;
    const float s = G[o] / sqrtf(Bv[o] + 1e-5f);
    const float beo = Be[o];
    const float bo = Bs[o];
    const float mo = Bm[o];

    float mx = -INFINITY;
    for (int k = 0; k < KNB; ++k) {
        float y = 0.f;
        for (int c = 0; c < CIN; ++c) y += wr[c] * (nb[k][c] - ctr[c]);
        for (int c = 0; c < CIN; ++c) y += wr[CIN + c] * ctr[c];
        y += bo;
        float t = (y - mo) * s + beo;
        t = t > 0.f ? t : 0.2f * t;
        mx = fmaxf(mx, t);
    }
    Hout[(size_t)(base + q) * HC + off_out + o] = mx;
}

// ---------------- lc conv + BN + lrelu + max/mean pool, literal ----------------
__global__ __launch_bounds__(64) void lc_kernel(
    const float* __restrict__ H, const float* __restrict__ W, const float* __restrict__ Bs,
    const float* __restrict__ G, const float* __restrict__ Be,
    const float* __restrict__ Bm, const float* __restrict__ Bv,
    float* __restrict__ h2)
{
    __shared__ float hchunk[16][HC];   // 32 KB
    const int bx = blockIdx.x;         // 16*16
    const int b = bx >> 4, o64 = bx & 15;
    const int tid = threadIdx.x;
    const int og = o64 * 64 + tid;
    const float* wr = W + (size_t)og * HC;
    const float s = G[og] / sqrtf(Bv[og] + 1e-5f);
    const float beo = Be[og];
    const float bo = Bs[og];
    const float mo = Bm[og];

    float mx = -INFINITY, sm = 0.f;
    for (int ch = 0; ch < 64; ++ch) {
        for (int t = tid; t < 16 * HC; t += 64) {
            const int nl = t >> 9, c = t & 511;
            hchunk[nl][c] = H[((size_t)(b * NPTS + ch * 16 + nl)) * HC + c];
        }
        __syncthreads();
        for (int nl = 0; nl < 16; ++nl) {
            float acc = 0.f;
            for (int c = 0; c < HC; ++c) acc += wr[c] * hchunk[nl][c];
            float t = (acc + bo - mo) * s + beo;
            t = t > 0.f ? t : 0.2f * t;
            mx = fmaxf(mx, t);
            sm += t;
        }
        __syncthreads();
    }
    h2[(size_t)b * 2048 + og] = mx;
    h2[(size_t)b * 2048 + 1024 + og] = sm * (1.f / 1024.f);
}

// ---------------- FC layers (literal) ----------------
__global__ void l0_kernel(const float* __restrict__ h2, const float* __restrict__ W,
                          const float* __restrict__ G, const float* __restrict__ Be,
                          const float* __restrict__ Bm, const float* __restrict__ Bv,
                          float* __restrict__ h3)
{
    const int i = blockIdx.x * 256 + threadIdx.x;
    if (i >= BB * 512) return;
    const int b = i >> 9, o = i & 511;
    const float* wr = W + (size_t)o * 2048;
    const float* hr = h2 + (size_t)b * 2048;
    float acc = 0.f;
    for (int c = 0; c < 2048; ++c) acc += wr[c] * hr[c];
    const float s = G[o] / sqrtf(Bv[o] + 1e-5f);
    float t = (acc - Bm[o]) * s + Be[o];
    t = t > 0.f ? t : 0.2f * t;
    h3[(size_t)b * 512 + o] = t;
}

__global__ void l1_kernel(const float* __restrict__ h3, const float* __restrict__ W,
                          const float* __restrict__ Bs, const float* __restrict__ G,
                          const float* __restrict__ Be, const float* __restrict__ Bm,
                          const float* __restrict__ Bv, float* __restrict__ h4o)
{
    const int i = blockIdx.x * 256 + threadIdx.x;
    if (i >= BB * 256) return;
    const int b = i >> 8, o = i & 255;
    const float* wr = W + (size_t)o * 512;
    const float* hr = h3 + (size_t)b * 512;
    float acc = 0.f;
    for (int c = 0; c < 512; ++c) acc += wr[c] * hr[c];
    acc += Bs[o];
    const float s = G[o] / sqrtf(Bv[o] + 1e-5f);
    float t = (acc - Bm[o]) * s + Be[o];
    t = t > 0.f ? t : 0.2f * t;
    h4o[(size_t)b * 256 + o] = t;
}

// FLOAT32 output — the reference returns float32; d_out is a float buffer.
__global__ void out_kernel(const float* __restrict__ h4, const float* __restrict__ W,
                           const float* __restrict__ Bs, float* __restrict__ out)
{
    const int i = blockIdx.x * 256 + threadIdx.x;
    if (i >= BB * 40) return;
    const int b = i / 40, o = i % 40;
    const float* wr = W + (size_t)o * 256;
    const float* hr = h4 + (size_t)b * 256;
    float acc = 0.f;
    for (int c = 0; c < 256; ++c) acc += wr[c] * hr[c];
    acc += Bs[o];
    out[(size_t)b * 40 + o] = acc;
}

extern "C" void kernel_launch(void* const* d_in, const int* in_sizes, int n_in,
                              void* d_out, int out_size, void* d_ws, size_t ws_size,
                              hipStream_t stream)
{
    static const int expect[44] = {
        49152, 384,64,64,64,64,64, 8192,64,64,64,64,64, 16384,128,128,128,128,128,
        65536,256,256,256,256,256, 524288,1024,1024,1024,1024,1024,
        1048576,512,512,512,512, 131072,256,256,256,256,256, 10240,40};
    int bad = -1;
    if (n_in != 44) bad = 100;
    else if (out_size != BB * 40) bad = 101;
    else {
        for (int i = 0; i < 44; ++i) if (in_sizes[i] != expect[i]) { bad = i; break; }
    }
    if (bad >= 0) {
        sentinel_kernel<<<3, 256, 0, stream>>>((float*)d_out, 500.f + (float)bad);
        return;
    }

    const float* X = (const float*)d_in[0];
    const float *CW[4], *CB[4], *CG[4], *CBE[4], *CM[4], *CV[4];
    for (int i = 0; i < 4; ++i) {
        CW[i]  = (const float*)d_in[1 + 6*i]; CB[i] = (const float*)d_in[2 + 6*i];
        CG[i]  = (const float*)d_in[3 + 6*i]; CBE[i] = (const float*)d_in[4 + 6*i];
        CM[i]  = (const float*)d_in[5 + 6*i]; CV[i] = (const float*)d_in[6 + 6*i];
    }
    const float* LCW = (const float*)d_in[25]; const float* LCB = (const float*)d_in[26];
    const float* LCG = (const float*)d_in[27]; const float* LCBE = (const float*)d_in[28];
    const float* LCM = (const float*)d_in[29]; const float* LCV = (const float*)d_in[30];
    const float* L0W = (const float*)d_in[31]; const float* L0G = (const float*)d_in[32];
    const float* L0BE = (const float*)d_in[33]; const float* L0M = (const float*)d_in[34];
    const float* L0V = (const float*)d_in[35];
    const float* L1W = (const float*)d_in[36]; const float* L1B = (const float*)d_in[37];
    const float* L1G = (const float*)d_in[38]; const float* L1BE = (const float*)d_in[39];
    const float* L1M = (const float*)d_in[40]; const float* L1V = (const float*)d_in[41];
    const float* OW = (const float*)d_in[42]; const float* OB = (const float*)d_in[43];

    float* H    = (float*)d_ws;                           // 16*1024*512 f32 = 32 MB
    float* XX   = H + (size_t)BB * NPTS * HC;             // 16384 f32
    int*   IDX  = (int*)(XX + BB * NPTS);                 // 16*1024*20 int
    float* H2   = (float*)(IDX + (size_t)BB * NPTS * KNB);// 16*2048
    float* H3   = H2 + BB * 2048;                         // 16*512
    float* H4   = H3 + BB * 512;                          // 16*256

    // ---- layer 0 (x as (b,n,3) row-major, per reference) ----
    xx_kernel<<<BB*NPTS/256, 256, 0, stream>>>(H, X, XX, 3, 0, 1);
    knn_kernel<<<BB*NPTS, 256, 0, stream>>>(H, X, XX, IDX, 3, 0, 1);
    conv_kernel<3,64,true><<<BB*NPTS, 64, 0, stream>>>(H, X, IDX,
        CW[0], CB[0], CG[0], CBE[0], CM[0], CV[0], H, 0, 0);

    // ---- layer 1 ----
    xx_kernel<<<BB*NPTS/256, 256, 0, stream>>>(H, X, XX, 64, 0, 0);
    knn_kernel<<<BB*NPTS, 256, 0, stream>>>(H, X, XX, IDX, 64, 0, 0);
    conv_kernel<64,64,false><<<BB*NPTS, 64, 0, stream>>>(H, X, IDX,
        CW[1], CB[1], CG[1], CBE[1], CM[1], CV[1], H, 0, 64);

    // ---- layer 2 ----
    xx_kernel<<<BB*NPTS/256, 256, 0, stream>>>(H, X, XX, 64, 64, 0);
    knn_kernel<<<BB*NPTS, 256, 0, stream>>>(H, X, XX, IDX, 64, 64, 0);
    conv_kernel<64,128,false><<<BB*NPTS, 128, 0, stream>>>(H, X, IDX,
        CW[2], CB[2], CG[2], CBE[2], CM[2], CV[2], H, 64, 128);

    // ---- layer 3 ----
    xx_kernel<<<BB*NPTS/256, 256, 0, stream>>>(H, X, XX, 128, 128, 0);
    knn_kernel<<<BB*NPTS, 256, 0, stream>>>(H, X, XX, IDX, 128, 128, 0);
    conv_kernel<128,256,false><<<BB*NPTS, 256, 0, stream>>>(H, X, IDX,
        CW[3], CB[3], CG[3], CBE[3], CM[3], CV[3], H, 128, 256);

    // ---- lc conv + pooling ----
    lc_kernel<<<BB*16, 64, 0, stream>>>(H, LCW, LCB, LCG, LCBE, LCM, LCV, H2);

    // ---- FC head (f32 output) ----
    l0_kernel<<<(BB*512+255)/256, 256, 0, stream>>>(H2, L0W, L0G, L0BE, L0M, L0V, H3);
    l1_kernel<<<(BB*256+255)/256, 256, 0, stream>>>(H3, L1W, L1B, L1G, L1BE, L1M, L1V, H4);
    out_kernel<<<(BB*40+255)/256, 256, 0, stream>>>(H4, OW, OB, (float*)d_out);
}

// Round 9
// 3940.850 us; speedup vs baseline: 4.0104x; 4.0104x over previous
//
#include <hip/hip_runtime.h>
#include <hip/hip_bf16.h>

#define BB 16
#define NPTS 1024
#define KNB 20
#define HC 512

// x stored row-major (b, n, c): x[b,n,c] at X[(b*1024+n)*3 + c]  (per reference setup_inputs)
__device__ __forceinline__ float XV(const float* __restrict__ X, int b, int n, int c)
{
    return X[((size_t)b * NPTS + n) * 3 + c];
}

// ---------------- sentinel (diagnostic) ----------------
__global__ void sentinel_kernel(float* __restrict__ out, float val)
{
    const int i = blockIdx.x * 256 + threadIdx.x;
    if (i < BB * 40) out[i] = val;
}

// ---------------- squared norms ----------------
__global__ void xx_kernel(const float* __restrict__ H, const float* __restrict__ X,
                          float* __restrict__ xx, int cin, int off_in, int use_x)
{
    const int p = blockIdx.x * blockDim.x + threadIdx.x;
    if (p >= BB * NPTS) return;
    float s = 0.f;
    if (use_x) {
        const int b = p >> 10, n = p & 1023;
        for (int c = 0; c < 3; ++c) { const float v = XV(X, b, n, c); s += v * v; }
    } else {
        const float4* r4 = (const float4*)(H + (size_t)p * HC + off_in);
        for (int c4 = 0; c4 < cin / 4; ++c4) {
            const float4 v = r4[c4];
            s += v.x*v.x + v.y*v.y + v.z*v.z + v.w*v.w;
        }
    }
    xx[p] = s;
}

// ---------------- knn top-20, wave-parallel ----------------
__global__ __launch_bounds__(256) void knn_kernel(
    const float* __restrict__ H, const float* __restrict__ X, const float* __restrict__ xx,
    int* __restrict__ idxo, int cin, int off_in, int use_x)
{
    __shared__ __align__(16) float qv[128];
    __shared__ float dist[NPTS];
    __shared__ unsigned long long wred[4];
    __shared__ int winner;

    const int blk = blockIdx.x;
    const int b = blk >> 10, q = blk & 1023;
    const int tid = threadIdx.x;
    const int base = b * NPTS;

    if (use_x) {
        if (tid < 3) qv[tid] = XV(X, b, q, tid);
    } else {
        for (int c = tid; c < cin; c += 256) qv[c] = H[(size_t)(base + q) * HC + off_in + c];
    }
    __syncthreads();
    const float xxq = xx[base + q];

    for (int j = 0; j < 4; ++j) {
        const int m = tid + 256 * j;
        float acc = 0.f;
        if (use_x) {
            acc = qv[0] * XV(X, b, m, 0) + qv[1] * XV(X, b, m, 1) + qv[2] * XV(X, b, m, 2);
        } else {
            const float4* r4 = (const float4*)(H + (size_t)(base + m) * HC + off_in);
            for (int c4 = 0; c4 < cin / 4; ++c4) {
                const float4 v = r4[c4];
                acc += qv[4*c4] * v.x + qv[4*c4+1] * v.y + qv[4*c4+2] * v.z + qv[4*c4+3] * v.w;
            }
        }
        dist[m] = (2.f * acc - xxq) - xx[base + m];
    }
    __syncthreads();

    const int lane = tid & 63, wv = tid >> 6;
    for (int it = 0; it < KNB; ++it) {
        unsigned long long best = 0ull;
        for (int j = 0; j < 4; ++j) {
            const int m = tid + 256 * j;
            unsigned u = __float_as_uint(dist[m]);
            u = (u & 0x80000000u) ? ~u : (u | 0x80000000u);   // sortable float
            const unsigned long long key = ((unsigned long long)u << 32) | (unsigned)(1023 - m);
            if (key > best) best = key;
        }
        for (int off = 32; off > 0; off >>= 1) {
            const unsigned long long o = __shfl_down(best, off, 64);
            if (o > best) best = o;
        }
        if (lane == 0) wred[wv] = best;
        __syncthreads();
        if (tid == 0) {
            unsigned long long bb = wred[0];
            for (int i2 = 1; i2 < 4; ++i2) if (wred[i2] > bb) bb = wred[i2];
            const int widx = 1023 - (int)(bb & 0xFFFFFFFFull);
            winner = widx;
            idxo[(size_t)(base + q) * KNB + it] = widx;
        }
        __syncthreads();
        if (tid == (winner & 255)) dist[winner] = -INFINITY;
        __syncthreads();
    }
}

// ---------------- edge conv: folded center term + float4 ----------------
// y_k = sum_c w1[c]*nb[k][c] + (sum_c (w2[c]-w1[c])*ctr[c]) + bias  (algebraic fold)
template<int CIN, int COUT, bool USEX>
__global__ __launch_bounds__(COUT) void conv_kernel(
    const float* __restrict__ H, const float* __restrict__ X, const int* __restrict__ idx,
    const float* __restrict__ W, const float* __restrict__ Bs, const float* __restrict__ G,
    const float* __restrict__ Be, const float* __restrict__ Bm, const float* __restrict__ Bv,
    float* __restrict__ Hout, int off_in, int off_out)
{
    __shared__ __align__(16) float ctr[CIN];
    __shared__ __align__(16) float nb[KNB][CIN];
    __shared__ int sidx[KNB];
    const int blk = blockIdx.x;
    const int b = blk >> 10, q = blk & 1023;
    const int tid = threadIdx.x;
    const int base = b * NPTS;

    if (tid < KNB) sidx[tid] = idx[(size_t)(base + q) * KNB + tid];
    for (int c = tid; c < CIN; c += COUT)
        ctr[c] = USEX ? XV(X, b, q, c)
                      : H[(size_t)(base + q) * HC + off_in + c];
    __syncthreads();
    for (int t = tid; t < KNB * CIN; t += COUT) {
        const int k = t / CIN, c = t - k * CIN;
        const int src = sidx[k];
        nb[k][c] = USEX ? XV(X, b, src, c)
                        : H[(size_t)(base + src) * HC + off_in + c];
    }
    __syncthreads();

    const int o = tid;
    float acc[KNB];
#pragma unroll
    for (int k = 0; k < KNB; ++k) acc[k] = 0.f;
    float cacc = 0.f;

    if constexpr (CIN % 4 == 0) {
        const float4* w4 = (const float4*)(W + (size_t)o * 2 * CIN);
        for (int c4 = 0; c4 < CIN / 4; ++c4) {
            const float4 w1 = w4[c4];
            const float4 w2 = w4[CIN / 4 + c4];
            const float4 cv = *(const float4*)&ctr[4 * c4];
            cacc += (w2.x - w1.x) * cv.x + (w2.y - w1.y) * cv.y
                  + (w2.z - w1.z) * cv.z + (w2.w - w1.w) * cv.w;
#pragma unroll
            for (int k = 0; k < KNB; ++k) {
                const float4 nv = *(const float4*)&nb[k][4 * c4];
                acc[k] += w1.x * nv.x + w1.y * nv.y + w1.z * nv.z + w1.w * nv.w;
            }
        }
    } else {
        const float* wr = W + (size_t)o * 2 * CIN;
        for (int c = 0; c < CIN; ++c) {
            const float w1 = wr[c], w2 = wr[CIN + c];
            cacc += (w2 - w1) * ctr[c];
#pragma unroll
            for (int k = 0; k < KNB; ++k) acc[k] += w1 * nb[k][c];
        }
    }

    const float s = G[o] / sqrtf(Bv[o] + 1e-5f);
    const float beo = Be[o];
    const float cb = cacc + Bs[o] - Bm[o];
    float mx = -INFINITY;
#pragma unroll
    for (int k = 0; k < KNB; ++k) {
        float t = (acc[k] + cb) * s + beo;
        t = t > 0.f ? t : 0.2f * t;
        mx = fmaxf(mx, t);
    }
    Hout[(size_t)(base + q) * HC + off_out + o] = mx;
}

// ---------------- lc conv (512->1024) + BN + lrelu + partial max/mean pool ----------------
// grid: 16 b x 16 o-blk(64) x 8 n-blk(128). 256 thr: o = tid&63, grp = tid>>6 handles 32 n.
__global__ __launch_bounds__(256) void lcpool_kernel(
    const float* __restrict__ H, const float* __restrict__ W, const float* __restrict__ Bs,
    const float* __restrict__ G, const float* __restrict__ Be,
    const float* __restrict__ Bm, const float* __restrict__ Bv,
    float* __restrict__ pmax, float* __restrict__ psum)
{
    __shared__ float hl[32][132];   // [c][n], padded
    __shared__ float wl[32][65];    // [c][o], padded
    __shared__ float redm[4][64];
    __shared__ float reds[4][64];
    const int bid = blockIdx.x;            // 16*16*8
    const int b = bid >> 7;
    const int rem = bid & 127;
    const int oblk = rem >> 3;
    const int nblk = rem & 7;
    const int tid = threadIdx.x;
    const int o = tid & 63;
    const int grp = tid >> 6;
    const int og = oblk * 64 + o;
    const int n0 = nblk * 128;
    const size_t hbase = (size_t)b * NPTS * HC;

    float acc[32];
#pragma unroll
    for (int i = 0; i < 32; ++i) acc[i] = 0.f;

    for (int ct = 0; ct < 16; ++ct) {
        for (int r = 0; r < 4; ++r) {
            const int e = tid + 256 * r;     // 1024 float4s
            const int n = e & 127, c4 = e >> 7;
            const float4 hv = *(const float4*)(H + hbase + (size_t)(n0 + n) * HC + ct * 32 + c4 * 4);
            hl[c4*4+0][n] = hv.x; hl[c4*4+1][n] = hv.y; hl[c4*4+2][n] = hv.z; hl[c4*4+3][n] = hv.w;
        }
        for (int r = 0; r < 8; ++r) {
            const int e = tid + 256 * r;     // 2048
            const int c_ = e & 31, o_ = e >> 5;
            wl[c_][o_] = W[(size_t)(oblk * 64 + o_) * HC + ct * 32 + c_];
        }
        __syncthreads();
        for (int c = 0; c < 32; ++c) {
            const float wv = wl[c][o];
            const float* hr = &hl[c][grp * 32];
#pragma unroll
            for (int nn = 0; nn < 8; ++nn) {
                const float4 hv = *(const float4*)(hr + 4 * nn);
                acc[4*nn+0] += wv * hv.x; acc[4*nn+1] += wv * hv.y;
                acc[4*nn+2] += wv * hv.z; acc[4*nn+3] += wv * hv.w;
            }
        }
        __syncthreads();
    }

    const float s = G[og] / sqrtf(Bv[og] + 1e-5f);
    const float beo = Be[og];
    const float mb = Bs[og] - Bm[og];
    float pm = -INFINITY, ps = 0.f;
#pragma unroll
    for (int i = 0; i < 32; ++i) {
        float t = (acc[i] + mb) * s + beo;
        t = t > 0.f ? t : 0.2f * t;
        pm = fmaxf(pm, t); ps += t;
    }
    redm[grp][o] = pm; reds[grp][o] = ps;
    __syncthreads();
    if (grp == 0) {
        float m0 = redm[0][o], s0 = reds[0][o];
        for (int i2 = 1; i2 < 4; ++i2) { m0 = fmaxf(m0, redm[i2][o]); s0 += reds[i2][o]; }
        pmax[((size_t)b * 8 + nblk) * 1024 + og] = m0;
        psum[((size_t)b * 8 + nblk) * 1024 + og] = s0;
    }
}

__global__ void pool_reduce_kernel(const float* __restrict__ pmax, const float* __restrict__ psum,
                                   float* __restrict__ h2)
{
    const int i = blockIdx.x * 256 + threadIdx.x;   // 16*1024
    if (i >= BB * 1024) return;
    const int b = i >> 10, o = i & 1023;
    float mx = -INFINITY, sm = 0.f;
    for (int c = 0; c < 8; ++c) {
        mx = fmaxf(mx, pmax[((size_t)b * 8 + c) * 1024 + o]);
        sm += psum[((size_t)b * 8 + c) * 1024 + o];
    }
    h2[(size_t)b * 2048 + o] = mx;
    h2[(size_t)b * 2048 + 1024 + o] = sm * (1.f / 1024.f);
}

// ---------------- FC layers (float4) ----------------
__global__ void l0_kernel(const float* __restrict__ h2, const float* __restrict__ W,
                          const float* __restrict__ G, const float* __restrict__ Be,
                          const float* __restrict__ Bm, const float* __restrict__ Bv,
                          float* __restrict__ h3)
{
    const int i = blockIdx.x * 256 + threadIdx.x;
    if (i >= BB * 512) return;
    const int b = i >> 9, o = i & 511;
    const float4* w4 = (const float4*)(W + (size_t)o * 2048);
    const float4* h4p = (const float4*)(h2 + (size_t)b * 2048);
    float acc = 0.f;
    for (int c = 0; c < 512; ++c) {
        const float4 wv = w4[c]; const float4 hv = h4p[c];
        acc += wv.x*hv.x + wv.y*hv.y + wv.z*hv.z + wv.w*hv.w;
    }
    const float s = G[o] / sqrtf(Bv[o] + 1e-5f);
    float t = (acc - Bm[o]) * s + Be[o];
    t = t > 0.f ? t : 0.2f * t;
    h3[(size_t)b * 512 + o] = t;
}

__global__ void l1_kernel(const float* __restrict__ h3, const float* __restrict__ W,
                          const float* __restrict__ Bs, const float* __restrict__ G,
                          const float* __restrict__ Be, const float* __restrict__ Bm,
                          const float* __restrict__ Bv, float* __restrict__ h4o)
{
    const int i = blockIdx.x * 256 + threadIdx.x;
    if (i >= BB * 256) return;
    const int b = i >> 8, o = i & 255;
    const float4* w4 = (const float4*)(W + (size_t)o * 512);
    const float4* hv4 = (const float4*)(h3 + (size_t)b * 512);
    float acc = 0.f;
    for (int c = 0; c < 128; ++c) {
        const float4 wv = w4[c]; const float4 hv = hv4[c];
        acc += wv.x*hv.x + wv.y*hv.y + wv.z*hv.z + wv.w*hv.w;
    }
    acc += Bs[o];
    const float s = G[o] / sqrtf(Bv[o] + 1e-5f);
    float t = (acc - Bm[o]) * s + Be[o];
    t = t > 0.f ? t : 0.2f * t;
    h4o[(size_t)b * 256 + o] = t;
}

__global__ void out_kernel(const float* __restrict__ h4, const float* __restrict__ W,
                           const float* __restrict__ Bs, float* __restrict__ out)
{
    const int i = blockIdx.x * 256 + threadIdx.x;
    if (i >= BB * 40) return;
    const int b = i / 40, o = i % 40;
    const float4* w4 = (const float4*)(W + (size_t)o * 256);
    const float4* hv4 = (const float4*)(h4 + (size_t)b * 256);
    float acc = 0.f;
    for (int c = 0; c < 64; ++c) {
        const float4 wv = w4[c]; const float4 hv = hv4[c];
        acc += wv.x*hv.x + wv.y*hv.y + wv.z*hv.z + wv.w*hv.w;
    }
    acc += Bs[o];
    out[(size_t)b * 40 + o] = acc;
}

extern "C" void kernel_launch(void* const* d_in, const int* in_sizes, int n_in,
                              void* d_out, int out_size, void* d_ws, size_t ws_size,
                              hipStream_t stream)
{
    static const int expect[44] = {
        49152, 384,64,64,64,64,64, 8192,64,64,64,64,64, 16384,128,128,128,128,128,
        65536,256,256,256,256,256, 524288,1024,1024,1024,1024,1024,
        1048576,512,512,512,512, 131072,256,256,256,256,256, 10240,40};
    int bad = -1;
    if (n_in != 44) bad = 100;
    else if (out_size != BB * 40) bad = 101;
    else {
        for (int i = 0; i < 44; ++i) if (in_sizes[i] != expect[i]) { bad = i; break; }
    }
    if (bad >= 0) {
        sentinel_kernel<<<3, 256, 0, stream>>>((float*)d_out, 500.f + (float)bad);
        return;
    }

    const float* X = (const float*)d_in[0];
    const float *CW[4], *CB[4], *CG[4], *CBE[4], *CM[4], *CV[4];
    for (int i = 0; i < 4; ++i) {
        CW[i]  = (const float*)d_in[1 + 6*i]; CB[i] = (const float*)d_in[2 + 6*i];
        CG[i]  = (const float*)d_in[3 + 6*i]; CBE[i] = (const float*)d_in[4 + 6*i];
        CM[i]  = (const float*)d_in[5 + 6*i]; CV[i] = (const float*)d_in[6 + 6*i];
    }
    const float* LCW = (const float*)d_in[25]; const float* LCB = (const float*)d_in[26];
    const float* LCG = (const float*)d_in[27]; const float* LCBE = (const float*)d_in[28];
    const float* LCM = (const float*)d_in[29]; const float* LCV = (const float*)d_in[30];
    const float* L0W = (const float*)d_in[31]; const float* L0G = (const float*)d_in[32];
    const float* L0BE = (const float*)d_in[33]; const float* L0M = (const float*)d_in[34];
    const float* L0V = (const float*)d_in[35];
    const float* L1W = (const float*)d_in[36]; const float* L1B = (const float*)d_in[37];
    const float* L1G = (const float*)d_in[38]; const float* L1BE = (const float*)d_in[39];
    const float* L1M = (const float*)d_in[40]; const float* L1V = (const float*)d_in[41];
    const float* OW = (const float*)d_in[42]; const float* OB = (const float*)d_in[43];

    float* H    = (float*)d_ws;                           // 16*1024*512 f32 = 32 MB
    float* XX   = H + (size_t)BB * NPTS * HC;             // 16384 f32
    int*   IDX  = (int*)(XX + BB * NPTS);                 // 16*1024*20 int
    float* PMAX = (float*)(IDX + (size_t)BB * NPTS * KNB);// 16*8*1024
    float* PSUM = PMAX + BB * 8 * 1024;
    float* H2   = PSUM + BB * 8 * 1024;                   // 16*2048
    float* H3   = H2 + BB * 2048;                         // 16*512
    float* H4   = H3 + BB * 512;                          // 16*256

    // ---- layer 0 ----
    xx_kernel<<<BB*NPTS/256, 256, 0, stream>>>(H, X, XX, 3, 0, 1);
    knn_kernel<<<BB*NPTS, 256, 0, stream>>>(H, X, XX, IDX, 3, 0, 1);
    conv_kernel<3,64,true><<<BB*NPTS, 64, 0, stream>>>(H, X, IDX,
        CW[0], CB[0], CG[0], CBE[0], CM[0], CV[0], H, 0, 0);

    // ---- layer 1 ----
    xx_kernel<<<BB*NPTS/256, 256, 0, stream>>>(H, X, XX, 64, 0, 0);
    knn_kernel<<<BB*NPTS, 256, 0, stream>>>(H, X, XX, IDX, 64, 0, 0);
    conv_kernel<64,64,false><<<BB*NPTS, 64, 0, stream>>>(H, X, IDX,
        CW[1], CB[1], CG[1], CBE[1], CM[1], CV[1], H, 0, 64);

    // ---- layer 2 ----
    xx_kernel<<<BB*NPTS/256, 256, 0, stream>>>(H, X, XX, 64, 64, 0);
    knn_kernel<<<BB*NPTS, 256, 0, stream>>>(H, X, XX, IDX, 64, 64, 0);
    conv_kernel<64,128,false><<<BB*NPTS, 128, 0, stream>>>(H, X, IDX,
        CW[2], CB[2], CG[2], CBE[2], CM[2], CV[2], H, 64, 128);

    // ---- layer 3 ----
    xx_kernel<<<BB*NPTS/256, 256, 0, stream>>>(H, X, XX, 128, 128, 0);
    knn_kernel<<<BB*NPTS, 256, 0, stream>>>(H, X, XX, IDX, 128, 128, 0);
    conv_kernel<128,256,false><<<BB*NPTS, 256, 0, stream>>>(H, X, IDX,
        CW[3], CB[3], CG[3], CBE[3], CM[3], CV[3], H, 128, 256);

    // ---- lc conv + pooling ----
    lcpool_kernel<<<BB*16*8, 256, 0, stream>>>(H, LCW, LCB, LCG, LCBE, LCM, LCV, PMAX, PSUM);
    pool_reduce_kernel<<<BB*1024/256, 256, 0, stream>>>(PMAX, PSUM, H2);

    // ---- FC head (f32 output) ----
    l0_kernel<<<(BB*512+255)/256, 256, 0, stream>>>(H2, L0W, L0G, L0BE, L0M, L0V, H3);
    l1_kernel<<<(BB*256+255)/256, 256, 0, stream>>>(H3, L1W, L1B, L1G, L1BE, L1M, L1V, H4);
    out_kernel<<<(BB*40+255)/256, 256, 0, stream>>>(H4, OW, OB, (float*)d_out);
}